// Round 13
// baseline (66.800 us; speedup 1.0000x reference)
//
#include <hip/hip_runtime.h>

#define NN 2048
#define BB 4
#define IN_F 128
#define OUT_F 64

typedef __attribute__((ext_vector_type(8))) short short8;
typedef __attribute__((ext_vector_type(4))) float f32x4;
typedef __attribute__((ext_vector_type(4))) int i32x4;

__device__ __forceinline__ ushort f2bf(float f) {
  uint u = __float_as_uint(f);
  uint r = (u + 0x7fffu + ((u >> 16) & 1u)) >> 16;   // RNE, finite values
  return (ushort)r;
}
__device__ __forceinline__ float bf2f(ushort s) {
  return __uint_as_float(((uint)s) << 16);
}

// Prep kernel, two block ranges:
//  blocks [0,4096): adj -> 1-bit mask (pure 67 MB read stream, 2 MB write).
//    thread t packs 16 ints (4x i32x4 NT loads) into one ushort; bit g%16 of
//    ushort g/16 corresponds to adj flat index g.
//  blocks [4096,6144): wh = h@W rows (4 rows/block, 1/wave) -> Whbf bf16 +
//    el/er wave-reduced. VALU-heavy work overlaps the stream blocks.
__global__ __launch_bounds__(256) void prep_kernel(
    const float* __restrict__ h, const float* __restrict__ W,
    const float* __restrict__ a, const int* __restrict__ adj,
    ushort* __restrict__ Whbf, float* __restrict__ el,
    float* __restrict__ er, ushort* __restrict__ bits) {
  int blk = blockIdx.x;
  if (blk < 4096) {
    size_t base = (size_t)blk * 4096;           // 4096 ints per block
    int t = threadIdx.x;
    const i32x4* src = (const i32x4*)(adj + base) + t * 4;   // 16 ints/thread
    uint bv = 0;
    #pragma unroll
    for (int q = 0; q < 4; ++q) {
      i32x4 v = __builtin_nontemporal_load(&src[q]);
      bv |= (v.x > 0 ? 1u : 0u) << (q * 4);
      bv |= (v.y > 0 ? 2u : 0u) << (q * 4);
      bv |= (v.z > 0 ? 4u : 0u) << (q * 4);
      bv |= (v.w > 0 ? 8u : 0u) << (q * 4);
    }
    bits[base / 16 + t] = (ushort)bv;
  } else {
    int row = (blk - 4096) * 4 + (threadIdx.x >> 6);   // b*NN + n
    int o = threadIdx.x & 63;
    const float* hr = h + (size_t)row * IN_F;
    float wh = 0.f;
    #pragma unroll 8
    for (int f = 0; f < IN_F; ++f) wh += hr[f] * W[f * OUT_F + o];
    Whbf[(size_t)row * OUT_F + o] = f2bf(wh);
    float vl = wh * a[o];
    float vr = wh * a[OUT_F + o];
    #pragma unroll
    for (int d = 32; d > 0; d >>= 1) {
      vl += __shfl_down(vl, d);
      vr += __shfl_down(vr, d);
    }
    if (o == 0) { el[row] = vl; er[row] = vr; }
  }
}

// Kernel 1b: WhbfT[b][o][j] = Whbf[b][j][o] (bf16 transpose, 64x2048/batch).
__global__ __launch_bounds__(256) void transpose_kernel(
    const ushort* __restrict__ Whbf, ushort* __restrict__ WhbfT) {
  __shared__ uint tile[64][65];
  int b = blockIdx.x >> 5;
  int j0 = (blockIdx.x & 31) << 6;
  int t = threadIdx.x;
  int o = t & 63, jg = t >> 6;
  #pragma unroll
  for (int m = 0; m < 16; ++m) {
    int jj = jg * 16 + m;
    tile[jj][o] = (uint)Whbf[((size_t)(b * NN + j0 + jj)) * OUT_F + o];
  }
  __syncthreads();
  int oo = t >> 2, grp = t & 3;
  uint out[8];
  #pragma unroll
  for (int m = 0; m < 16; m += 2) {
    uint u0 = tile[grp * 16 + m][oo];
    uint u1 = tile[grp * 16 + m + 1][oo];
    out[m >> 1] = u0 | (u1 << 16);
  }
  uint4* dst = (uint4*)(WhbfT + ((size_t)(b * OUT_F + oo)) * NN + j0 + grp * 16);
  dst[0] = *(uint4*)&out[0];
  dst[1] = *(uint4*)&out[4];
}

// Kernel 2: block = 16 rows, 512 threads (8 waves). adj comes from the 1-bit
// mask (one uint load + 8 shfls per row, L2/L3-resident) -> the kernel's only
// HBM stream is the 67 MB attention write (pure write stream).
// Phase 1 (all 8 waves): masked exp for 2 rows/wave, unnormalized bf16 p ->
//   swizzled pbuf; one barrier.
// Phase 2, waves 0-3: full-K MFMA p @ Wh for one 16-o tile -> hprime.
// Phase 2, waves 4-7: normalize p from LDS -> stream attention stores.
__global__ __launch_bounds__(512, 4) void attn_kernel(
    const ushort* __restrict__ bits, const ushort* __restrict__ WhbfT,
    const float* __restrict__ el, const float* __restrict__ er,
    float* __restrict__ attn_out, float* __restrict__ hprime) {
  __shared__ __align__(16) char pbuf[16 * 4096];  // 64 KB: p bf16 [16][2048]
  __shared__ float ers[NN];                       // 8 KB
  __shared__ float sinv[16];

  int blk = blockIdx.x;
  int b = blk >> 7;             // 128 blocks per batch
  int i0 = (blk & 127) << 4;
  int tid = threadIdx.x;
  int wave = tid >> 6, lane = tid & 63;

  // stage er for this batch into LDS
  ((f32x4*)ers)[tid] = ((const f32x4*)(er + (size_t)b * NN))[tid];
  __syncthreads();

  // ---- Phase 1: masked exp from bitmask, 2 rows per wave ----
  int r0 = wave * 2, r1 = r0 + 1;
  int ia = i0 + r0, ib = i0 + r1;
  float el0 = el[(size_t)b * NN + ia];
  float el1 = el[(size_t)b * NN + ib];
  // row bitmask: 2048 bits = 64 uints; lane loads word `lane`
  uint wl0 = ((const uint*)bits)[(size_t)(b * NN + ia) * 64 + lane];
  uint wl1 = ((const uint*)bits)[(size_t)(b * NN + ib) * 64 + lane];
  int srcbase = lane >> 3, nsh = (lane & 7) * 4;

  uint2 pva0[8], pva1[8];
  float ss0 = 0.f, ss1 = 0.f;
  #pragma unroll
  for (int it = 0; it < 8; ++it) {
    uint n0 = (__shfl(wl0, srcbase + 8 * it) >> nsh) & 0xF;
    uint n1 = (__shfl(wl1, srcbase + 8 * it) >> nsh) & 0xF;
    f32x4 ev = *(const f32x4*)&ers[(lane + 64 * it) * 4];
    float evv[4] = {ev.x, ev.y, ev.z, ev.w};
    float pe0[4], pe1[4];
    #pragma unroll
    for (int k = 0; k < 4; ++k) {
      float e0 = el0 + evv[k];
      e0 = fmaxf(e0, 0.2f * e0);            // leaky_relu 0.2
      float x0 = __expf(e0);                // |e| <~ 12, f32-safe unnormalized
      pe0[k] = (n0 >> k) & 1 ? x0 : 0.f;
      ss0 += pe0[k];
      float e1 = el1 + evv[k];
      e1 = fmaxf(e1, 0.2f * e1);
      float x1 = __expf(e1);
      pe1[k] = (n1 >> k) & 1 ? x1 : 0.f;
      ss1 += pe1[k];
    }
    uint2 w0, w1;
    w0.x = (uint)f2bf(pe0[0]) | ((uint)f2bf(pe0[1]) << 16);
    w0.y = (uint)f2bf(pe0[2]) | ((uint)f2bf(pe0[3]) << 16);
    w1.x = (uint)f2bf(pe1[0]) | ((uint)f2bf(pe1[1]) << 16);
    w1.y = (uint)f2bf(pe1[2]) | ((uint)f2bf(pe1[3]) << 16);
    pva0[it] = w0;
    pva1[it] = w1;
  }
  #pragma unroll
  for (int d = 32; d > 0; d >>= 1) {
    ss0 += __shfl_xor(ss0, d);
    ss1 += __shfl_xor(ss1, d);
  }
  if (lane == 0) { sinv[r0] = 1.f / ss0; sinv[r1] = 1.f / ss1; }

  // ---- p -> swizzled LDS (no global stores before the barrier) ----
  {
    char* lr0 = pbuf + r0 * 4096;
    char* lr1 = pbuf + r1 * 4096;
    int sw0 = (r0 & 7) << 4, sw1 = (r1 & 7) << 4;
    #pragma unroll
    for (int it = 0; it < 8; ++it) {
      *(uint2*)(lr0 + (((lane + 64 * it) * 8) ^ sw0)) = pva0[it];
      *(uint2*)(lr1 + (((lane + 64 * it) * 8) ^ sw1)) = pva1[it];
    }
  }
  __syncthreads();

  if (wave < 4) {
    // ---- MFMA consumer waves: full K for o-tile `wave`, loads only ----
    int o0 = wave * 16;
    int lo16 = lane & 15, hi4 = lane >> 4;
    const char* prowA = pbuf + lo16 * 4096;
    int swA = (lo16 & 7) << 4;
    const ushort* brow = WhbfT + ((size_t)(b * OUT_F + o0 + lo16)) * NN;

    f32x4 acc0 = {0.f, 0.f, 0.f, 0.f};
    f32x4 acc1 = {0.f, 0.f, 0.f, 0.f};
    #pragma unroll 8
    for (int kk = 0; kk < 32; ++kk) {
      int ka = kk * 32 + hi4 * 8;
      int kb = ka + 1024;
      short8 af0 = *(const short8*)(prowA + ((ka * 2) ^ swA));
      short8 bf0 = *(const short8*)(brow + ka);
      acc0 = __builtin_amdgcn_mfma_f32_16x16x32_bf16(af0, bf0, acc0, 0, 0, 0);
      short8 af1 = *(const short8*)(prowA + ((kb * 2) ^ swA));
      short8 bf1 = *(const short8*)(brow + kb);
      acc1 = __builtin_amdgcn_mfma_f32_16x16x32_bf16(af1, bf1, acc1, 0, 0, 0);
    }
    #pragma unroll
    for (int q = 0; q < 4; ++q) {
      int crow = hi4 * 4 + q;
      float v = (acc0[q] + acc1[q]) * sinv[crow];
      v = v > 0.f ? v : 0.01f * v;           // leaky_relu 0.01
      hprime[((size_t)(b * NN + i0 + crow)) * OUT_F + o0 + lo16] = v;
    }
  } else {
    // ---- store engine waves: normalize + stream attention rows ----
    #pragma unroll
    for (int m = 0; m < 4; ++m) {
      int r = (wave - 4) * 4 + m;
      float inv = sinv[r];
      const char* lr = pbuf + r * 4096;
      int sw = (r & 7) << 4;
      f32x4* orow = (f32x4*)(attn_out + ((size_t)(b * NN + i0 + r)) * NN);
      #pragma unroll
      for (int it = 0; it < 8; ++it) {
        uint2 w2 = *(const uint2*)(lr + (((lane + 64 * it) * 8) ^ sw));
        f32x4 v;
        v.x = bf2f((ushort)(w2.x & 0xffff)) * inv;
        v.y = bf2f((ushort)(w2.x >> 16)) * inv;
        v.z = bf2f((ushort)(w2.y & 0xffff)) * inv;
        v.w = bf2f((ushort)(w2.y >> 16)) * inv;
        orow[lane + 64 * it] = v;
      }
    }
  }
}

extern "C" void kernel_launch(void* const* d_in, const int* in_sizes, int n_in,
                              void* d_out, int out_size, void* d_ws, size_t ws_size,
                              hipStream_t stream) {
  const float* h  = (const float*)d_in[0];
  const int* adj  = (const int*)d_in[1];
  const float* W  = (const float*)d_in[2];
  const float* a  = (const float*)d_in[3];

  float* hprime   = (float*)d_out;                           // B*N*OUT_F
  float* attn_out = (float*)d_out + (size_t)BB * NN * OUT_F; // B*N*N

  // workspace: Whbf bf16 (1 MB), WhbfT bf16 (1 MB), el/er (64 KB), bits (2 MB)
  ushort* Whbf  = (ushort*)d_ws;
  ushort* WhbfT = Whbf + (size_t)BB * NN * OUT_F;
  float* el = (float*)(WhbfT + (size_t)BB * OUT_F * NN);
  float* er = el + (size_t)BB * NN;
  ushort* bits = (ushort*)(er + (size_t)BB * NN);

  hipLaunchKernelGGL(prep_kernel, dim3(4096 + BB * NN / 4), dim3(256), 0, stream,
                     h, W, a, adj, Whbf, el, er, bits);
  hipLaunchKernelGGL(transpose_kernel, dim3(BB * (NN / 64)), dim3(256), 0, stream,
                     Whbf, WhbfT);
  hipLaunchKernelGGL(attn_kernel, dim3(BB * (NN / 16)), dim3(512), 0, stream,
                     bits, WhbfT, el, er, attn_out, hprime);
}